// Round 5
// baseline (200.976 us; speedup 1.0000x reference)
//
#include <hip/hip_runtime.h>

// Problem constants (from reference)
#define VOCAB 50257
#define SEQ   2048
#define EMB   512
#define BATCH 8
#define NTOK  (BATCH * SEQ)   // 16384

typedef float floatx4 __attribute__((ext_vector_type(4)));

// ---------------------------------------------------------------------------
// Scan-free fused embedding gather, vectorized staging.
//
// Index build (2 tiny kernels, ~4 us):
//   head[v] : last output-row using vocab v, -1 if unused   (VOCAB ints)
//   next[i] : previous row with the same token as row i     (NTOK ints)
//
// slab_scatter_k, grid (197, 16), 256 thr, 4 blocks/CU:
//   Tile = 256 vocab x 32 emb.  slab[32][257] (33 KB, pad -> drain reads
//   land on banks (l'+vl)%32: conflict-free).
//   Staging: VOCAB%4==1 and v0%4==0  =>  row misalignment shift = e & 3.
//   Each lane reads ONE aligned dwordx4 from (row_base - shift) + 4*lane
//   (16 B/lane, 1 KB/wave-inst, fully coalesced; 8 loads/lane total vs 32
//   scalars before), writes LDS at col 4*lane - shift (lane-0 head
//   predicated, <=3 tail scalars per row).  All addresses proven in-bounds
//   for non-edge blocks; edge vocab block (bx==196) takes a predicated
//   scalar path.
//   Drain: two matches per wave (one per half-wave); per chain hop each
//   half-wave writes a full line-aligned 128 B out segment:
//   out[p][e0+l'] = slab[l'][vl] + Wpos[p&2047][e0+l']  (single fused f32
//   add, bit-identical to reference), nontemporal => no RFO.
//
// Traffic: W_emb read once (100.6 MB), out written once (33.5 MB),
// Wpos/head/next from L2.  Floor ~21 us @ 6.3 TB/s.
// ---------------------------------------------------------------------------

#define HEAD_OFF 0
#define NEXT_OFF 50432                // head padded to 50432
#define WS_INTS  (NEXT_OFF + NTOK)    // ~267 KB

#define VTILE 256
#define ETILE 32
#define NBX   197                     // ceil(VOCAB/VTILE)
#define SLDS  257                     // LDS row stride (dwords)

__global__ __launch_bounds__(256)
void init_head_k(int* __restrict__ head) {
    const int i = blockIdx.x * 256 + threadIdx.x;
    if (i < VOCAB) head[i] = -1;
}

__global__ __launch_bounds__(256)
void links_k(const int* __restrict__ tokens, int* __restrict__ head,
             int* __restrict__ next) {
    const int i = blockIdx.x * 256 + threadIdx.x;   // grid = NTOK/256
    next[i] = atomicExch(&head[tokens[i]], i);
}

__global__ __launch_bounds__(256, 4)
void slab_scatter_k(const int* __restrict__ head,
                    const int* __restrict__ next,
                    const float* __restrict__ W,      // (EMB, VOCAB)
                    const float* __restrict__ Wpos,   // (SEQ, EMB)
                    float* __restrict__ out) {        // (NTOK, EMB)
    __shared__ float slab[ETILE][SLDS];               // 32.9 KB
    __shared__ int   u_vl[VTILE];
    __shared__ int   u_hd[VTILE];
    __shared__ int   wcnt[4];

    const int bx   = blockIdx.x;
    const int v0   = bx * VTILE;
    const int e0   = blockIdx.y * ETILE;
    const int tid  = threadIdx.x;
    const int lane = tid & 63;
    const int wv   = tid >> 6;

    // --- used-column ballot (wave wv owns vocab v0+64*wv .. +63) ---
    const int vme = v0 + wv * 64 + lane;
    const int h   = (vme < VOCAB) ? head[vme] : -1;
    const unsigned long long m = __ballot(h >= 0);
    const int pos = (int)__popcll(m & ((1ull << lane) - 1ull));
    if (lane == 0) wcnt[wv] = (int)__popcll(m);

    // --- staging ---
    if (bx != NBX - 1) {
#pragma unroll
        for (int r8 = 0; r8 < 8; ++r8) {
            const int r = r8 * 4 + wv;                // e-row local
            const int e = e0 + r;
            const size_t A = (size_t)e * VOCAB + v0;  // dword index of row base
            const int shift = e & 3;                  // == A & 3 (VOCAB%4==1)
            const floatx4 x =
                *(reinterpret_cast<const floatx4*>(W + (A - shift)) + lane);
            const int c0 = 4 * lane - shift;          // >= -3 only for lane 0
#pragma unroll
            for (int i = 0; i < 4; ++i)
                if (c0 + i >= 0) slab[r][c0 + i] = x[i];
            if (lane < shift)                         // tail cols 256-shift..255
                slab[r][VTILE - shift + lane] = W[A + VTILE - shift + lane];
        }
    } else {
        // edge vocab block (81 valid cols): predicated scalar staging
#pragma unroll
        for (int r8 = 0; r8 < 8; ++r8) {
            const int r = r8 * 4 + wv;
            const size_t A = (size_t)(e0 + r) * VOCAB + v0;
#pragma unroll
            for (int j = 0; j < 4; ++j) {
                const int c = 64 * j + lane;
                if (v0 + c < VOCAB) slab[r][c] = W[A + c];
            }
        }
    }
    __syncthreads();                                  // wcnt + slab visible

    // --- place compacted entries ---
    int off = 0;
#pragma unroll
    for (int w = 0; w < 4; ++w)
        if (w < wv) off += wcnt[w];
    if (h >= 0) { u_vl[off + pos] = wv * 64 + lane; u_hd[off + pos] = h; }
    const int nused = wcnt[0] + wcnt[1] + wcnt[2] + wcnt[3];
    __syncthreads();                                  // u_* visible

    // --- chain-walk scatter: one match per HALF-wave ---
    const int half = lane >> 5;
    const int l32  = lane & 31;
    const float* wp = Wpos + e0 + l32;
    float*       op = out  + e0 + l32;
    for (int u = 2 * wv + half; u < nused; u += 8) {
        const int vl = u_vl[u];
        int p = u_hd[u];
        const float col = slab[l32][vl];              // (l32+vl)%32: free
        while (p >= 0) {
            const int s = p & (SEQ - 1);
            __builtin_nontemporal_store(col + wp[(size_t)s * EMB],
                                        op + (size_t)p * EMB);
            p = next[p];                              // ~1.15 hops avg, L2
        }
    }
}

// Fallback: direct strided gather (correct anywhere, slow).
__global__ __launch_bounds__(256)
void gather_direct_k(const int* __restrict__ tokens,
                     const float* __restrict__ W_emb,
                     const floatx4* __restrict__ Wpos,
                     floatx4* __restrict__ out) {
    const int idx = blockIdx.x * blockDim.x + threadIdx.x;
    const int e4  = idx & (EMB / 4 - 1);
    const int ts  = idx >> 7;
    const int s   = ts & (SEQ - 1);
    const int t   = tokens[ts];
    const size_t base = (size_t)(4 * e4) * VOCAB + (size_t)t;
    floatx4 r;
    r.x = W_emb[base];
    r.y = W_emb[base + (size_t)VOCAB];
    r.z = W_emb[base + (size_t)(2 * VOCAB)];
    r.w = W_emb[base + (size_t)(3 * VOCAB)];
    __builtin_nontemporal_store(r + Wpos[(size_t)s * (EMB / 4) + e4], &out[idx]);
}

extern "C" void kernel_launch(void* const* d_in, const int* in_sizes, int n_in,
                              void* d_out, int out_size, void* d_ws, size_t ws_size,
                              hipStream_t stream) {
    const int*   tokens = (const int*)d_in[0];
    const float* W_emb  = (const float*)d_in[1];   // (EMB, VOCAB)
    const float* W_pos  = (const float*)d_in[2];   // (SEQ, EMB)
    float*       out    = (float*)d_out;           // (BATCH*SEQ, EMB)

    const size_t need = (size_t)WS_INTS * sizeof(int);   // ~267 KB
    if (ws_size >= need) {
        int* head = (int*)d_ws + HEAD_OFF;
        int* next = (int*)d_ws + NEXT_OFF;

        init_head_k<<<(VOCAB + 255) / 256, 256, 0, stream>>>(head);
        links_k<<<NTOK / 256, 256, 0, stream>>>(tokens, head, next);
        slab_scatter_k<<<dim3(NBX, EMB / ETILE), 256, 0, stream>>>(
            head, next, W_emb, W_pos, out);
    } else {
        const int gblocks = BATCH * SEQ * (EMB / 4) / 256;
        gather_direct_k<<<gblocks, 256, 0, stream>>>(tokens, W_emb,
                                                     (const floatx4*)W_pos,
                                                     (floatx4*)out);
    }
}

// Round 6
// 177.159 us; speedup vs baseline: 1.1344x; 1.1344x over previous
//
#include <hip/hip_runtime.h>

// Problem constants (from reference)
#define VOCAB 50257
#define SEQ   2048
#define EMB   512
#define BATCH 8
#define NTOK  (BATCH * SEQ)   // 16384

typedef float floatx2 __attribute__((ext_vector_type(2)));
typedef float floatx4 __attribute__((ext_vector_type(4)));

// ---------------------------------------------------------------------------
// Scan-free fused embedding gather — round-4 structure, latency-optimized.
//
// Index build (2 tiny kernels):
//   head[v] : last output-row using vocab v, -1 if unused   (VOCAB ints)
//   next[i] : previous row with same token as row i         (NTOK ints)
//
// slab_scatter_k: 3144 blocks x 512 thr (8 waves), 64-vocab x 128-emb tile.
//   - Round-5 post-mortem: replay passes with FETCH~0 (W_emb L3-resident)
//     still took 76 us -> NOT BW-bound; bound by serial match loop x
//     dependent loads at 35% occupancy.  So: 8 waves/block (serial matches
//     per wave ~2.7, was ~5-10), 4 blocks/CU x 8 waves = 32 waves/CU.
//   - Staging: scalar coalesced (256 B/wave-inst), e-permuted slab[64][129]
//     (col = (e&1)*64 + e>>1) -> both staging writes and drain reads are
//     <=2-way bank-aliased = free (round-4 measured 0 conflicts; round-5's
//     vectorized LDS writes measured 2.4M -> reverted).
//   - Drain: full-wave floatx2 rows (512 B nontemporal), next[p] prefetched
//     before the Wpos load, single fused f32 add (bit-identical, absmax 0).
//   - XCD swizzle: bijective n->(bx,by) with by = (n&7)>>1 so each XCD's
//     L2 caches only its own 1 MB Wpos slice (per-hop Wpos = L2 hit).
// ---------------------------------------------------------------------------

#define HEAD_OFF 0
#define NEXT_OFF 50432                // head padded to 50432
#define WS_INTS  (NEXT_OFF + NTOK)    // ~267 KB

#define NBX   786                     // ceil(VOCAB/64)
#define NBLKS (NBX * 4)               // 3144 = 8 * 393

__global__ __launch_bounds__(256)
void init_head_k(int* __restrict__ head) {
    const int i = blockIdx.x * 256 + threadIdx.x;
    if (i < VOCAB) head[i] = -1;
}

__global__ __launch_bounds__(256)
void links_k(const int* __restrict__ tokens, int* __restrict__ head,
             int* __restrict__ next) {
    const int i = blockIdx.x * 256 + threadIdx.x;   // grid = NTOK/256
    next[i] = atomicExch(&head[tokens[i]], i);
}

__global__ __launch_bounds__(512, 8)
void slab_scatter_k(const int* __restrict__ head,
                    const int* __restrict__ next,
                    const float* __restrict__ W,       // (EMB, VOCAB)
                    const floatx2* __restrict__ Wpos2, // (SEQ, EMB/2)
                    floatx2* __restrict__ out2) {      // (NTOK, EMB/2)
    __shared__ float slab[64][129];                    // 33 KB
    __shared__ int   u_vl[64];
    __shared__ int   u_hd[64];
    __shared__ int   nused_s;

    // Bijective swizzle: XCD (= n%8, heuristic) gets a fixed e-quarter.
    const int n  = blockIdx.x;
    const int r  = n & 7;
    const int q  = n >> 3;                             // 0..392
    const int by = r >> 1;                             // e-quarter 0..3
    const int bx = 2 * q + (r & 1);                    // 0..785

    const int v0   = bx * 64;
    const int e0   = by * 128;
    const int tid  = threadIdx.x;
    const int lane = tid & 63;
    const int wv   = tid >> 6;                         // wave 0..7
    const int v    = v0 + lane;

    // --- used-column ballot + compact (wave 0 only, pre-barrier) ---
    if (wv == 0) {
        const int h = (v < VOCAB) ? head[v] : -1;
        const unsigned long long m = __ballot(h >= 0);
        const int pos = (int)__popcll(m & ((1ull << lane) - 1ull));
        if (h >= 0) { u_vl[pos] = lane; u_hd[pos] = h; }
        if (lane == 0) nused_s = (int)__popcll(m);
    }

    // --- staged, permuted slab load (all 8 waves; 16 rows each) ---
    if (v < VOCAB) {
        const float* rp = W + (size_t)(e0 + wv) * VOCAB + v;
        const int cb = (wv & 1) * 64 + (wv >> 1);
#pragma unroll
        for (int j = 0; j < 16; ++j) {
            // e' = 8j + wv -> col (e'&1)*64 + (e'>>1) = cb + 4j
            slab[lane][cb + 4 * j] = rp[(size_t)(8 * j) * VOCAB];
        }
    }
    __syncthreads();                                   // slab + list ready

    // --- chain-walk scatter: matches round-robin over 8 waves ---
    const int nused = nused_s;
    const int ecol2 = (e0 >> 1) + lane;                // floatx2 column
    for (int u = wv; u < nused; u += 8) {
        const int vl = u_vl[u];
        int p = u_hd[u];
        floatx2 col;
        col.x = slab[vl][lane];                        // e' = 2*lane
        col.y = slab[vl][64 + lane];                   // e' = 2*lane + 1
        while (p >= 0) {
            const int pn = next[p];                    // prefetch next hop
            const int s  = p & (SEQ - 1);
            const floatx2 r2 = col + Wpos2[(size_t)s * (EMB / 2) + ecol2];
            __builtin_nontemporal_store(
                r2, &out2[(size_t)p * (EMB / 2) + ecol2]);
            p = pn;
        }
    }
}

// Fallback: direct strided gather (correct anywhere, slow).
__global__ __launch_bounds__(256)
void gather_direct_k(const int* __restrict__ tokens,
                     const float* __restrict__ W_emb,
                     const floatx4* __restrict__ Wpos,
                     floatx4* __restrict__ out) {
    const int idx = blockIdx.x * blockDim.x + threadIdx.x;
    const int e4  = idx & (EMB / 4 - 1);
    const int ts  = idx >> 7;
    const int s   = ts & (SEQ - 1);
    const int t   = tokens[ts];
    const size_t base = (size_t)(4 * e4) * VOCAB + (size_t)t;
    floatx4 r;
    r.x = W_emb[base];
    r.y = W_emb[base + (size_t)VOCAB];
    r.z = W_emb[base + (size_t)(2 * VOCAB)];
    r.w = W_emb[base + (size_t)(3 * VOCAB)];
    __builtin_nontemporal_store(r + Wpos[(size_t)s * (EMB / 4) + e4], &out[idx]);
}

extern "C" void kernel_launch(void* const* d_in, const int* in_sizes, int n_in,
                              void* d_out, int out_size, void* d_ws, size_t ws_size,
                              hipStream_t stream) {
    const int*   tokens = (const int*)d_in[0];
    const float* W_emb  = (const float*)d_in[1];   // (EMB, VOCAB)
    const float* W_pos  = (const float*)d_in[2];   // (SEQ, EMB)
    float*       out    = (float*)d_out;           // (BATCH*SEQ, EMB)

    const size_t need = (size_t)WS_INTS * sizeof(int);   // ~267 KB
    if (ws_size >= need) {
        int* head = (int*)d_ws + HEAD_OFF;
        int* next = (int*)d_ws + NEXT_OFF;

        init_head_k<<<(VOCAB + 255) / 256, 256, 0, stream>>>(head);
        links_k<<<NTOK / 256, 256, 0, stream>>>(tokens, head, next);
        slab_scatter_k<<<NBLKS, 512, 0, stream>>>(
            head, next, W_emb, (const floatx2*)W_pos, (floatx2*)out);
    } else {
        const int gblocks = BATCH * SEQ * (EMB / 4) / 256;
        gather_direct_k<<<gblocks, 256, 0, stream>>>(tokens, W_emb,
                                                     (const floatx4*)W_pos,
                                                     (floatx4*)out);
    }
}